// Round 7
// baseline (750.274 us; speedup 1.0000x reference)
//
#include <hip/hip_runtime.h>

#define B_ 8192
#define T_ 36
#define F_ 36
#define N_ELEM (B_*T_*F_)   // 10616832
// bf16 xh scratch (ushort), 16B-aligned, inside fe/fem out regions
#define XHF_OFF (N_ELEM + 4)
#define XHB_OFF (2*N_ELEM + 4)

typedef __attribute__((ext_vector_type(8))) short bf16x8;
typedef __attribute__((ext_vector_type(4))) float f32x4;

__device__ inline short f2bf(float x){
  union { float f; unsigned u; } v; v.f = x;
  unsigned r = v.u + 0x7FFFu + ((v.u >> 16) & 1u);
  return (short)(r >> 16);
}
__device__ inline float bf2f(unsigned short u){
  union { unsigned u32; float f; } v; v.u32 = ((unsigned)u) << 16; return v.f;
}
// fast sigmoid/tanh: v_exp_f32 + v_rcp_f32, no IEEE divide, no clamp
// (exp2 saturates to 0/inf -> rcp gives exact 0/1 limits)
__device__ inline float sigm(float x){
  return __builtin_amdgcn_rcpf(1.f + __builtin_amdgcn_exp2f(-1.4426950408889634f * x));
}
__device__ inline float tanhc(float x){
  return __builtin_fmaf(2.f,
    __builtin_amdgcn_rcpf(1.f + __builtin_amdgcn_exp2f(-2.8853900817779268f * x)), -1.f);
}

// ws layout (bytes)
#define WS_WC   0         // bf16 [512][256]: cols 0..107=W_ih, 108..127=0, 128..255=W_hh
#define WS_WH   262144    // bf16 [2][64][128]: W_hist per direction, rows 36..63 = 0
#define WS_WP   294912    // bf16 [48][128]:   W_wc padded (k 72..127 = 0)
#define WS_BIAS 307200    // f32 [512]: b_ih + b_hh
#define WS_LACC 309248    // f32 [72][16]: num[t] at [t][0], den[t] at [36+t][0]

__global__ __launch_bounds__(256) void prep_kernel(
    const float* __restrict__ Wih, const float* __restrict__ Whh,
    const float* __restrict__ bih, const float* __restrict__ bhh,
    const float* __restrict__ Whist, const float* __restrict__ Wwc,
    char* __restrict__ ws)
{
  short* Wc   = (short*)(ws + WS_WC);
  short* Wh   = (short*)(ws + WS_WH);
  short* Wp   = (short*)(ws + WS_WP);
  float* bias = (float*)(ws + WS_BIAS);
  float* lacc = (float*)(ws + WS_LACC);
  int i = blockIdx.x*256 + threadIdx.x;
  if (i < 131072){
    int n = i >> 8, k = i & 255;
    float v = 0.f;
    if (k < 108) v = Wih[n*108 + k];
    else if (k >= 128) v = Whh[n*128 + (k - 128)];
    Wc[i] = f2bf(v);
  }
  if (i < 16384){
    int d = i >> 13, f = (i >> 7) & 63, k = i & 127;
    Wh[i] = (f < 36) ? f2bf(Whist[f*256 + d*128 + k]) : (short)0;
  }
  if (i < 6144){
    int f = i >> 7, k = i & 127;
    Wp[i] = (f < 36 && k < 72) ? f2bf(Wwc[f*72 + k]) : (short)0;
  }
  if (i < 512) bias[i] = bih[i] + bhh[i];
  if (i < 1152) lacc[i] = 0.f;
}

// Persistent LSTM: block = 32 rows x 1 dir, 8 waves, grid 512. Gate weights in
// registers. Inputs staged in 4-step chunks through an 8-slice LDS ring
// (one barrier per step, no double-barrier). Emit MFMA fused into gates kc 4..7.
// xh written via LDS slice as contiguous [t][b][f] bf16 stores.
__global__ __launch_bounds__(512, 2) void lstm_kernel(
  const float* __restrict__ fv, const float* __restrict__ fm, const float* __restrict__ fd,
  const float* __restrict__ bv, const float* __restrict__ bm, const float* __restrict__ bd,
  const char* __restrict__ ws, float* __restrict__ out)
{
  int dir = blockIdx.x & 1, tile = blockIdx.x >> 1;
  int b0 = tile * 32;
  const float* V = dir ? bv : fv;
  const float* M = dir ? bm : fm;
  const float* D = dir ? bd : fd;
  const short* Wc   = (const short*)(ws + WS_WC);
  const short* Wh   = (const short*)(ws + WS_WH) + dir*8192;
  const float* bias = (const float*)(ws + WS_BIAS);
  unsigned short* xhg = (unsigned short*)(out + (dir ? XHB_OFF : XHF_OFF)); // [t][b][f] bf16

  __shared__ short xch[8][4096];     // 8-slice ring of x t-slices [32][128] bf16, swizzled
  __shared__ short hb[2][4096];      // h double buffer [32][128] bf16, swizzled
  __shared__ float xhs[2][1280];     // xh slice dbuf [32][40] f32

  int tid = threadIdx.x, w = tid >> 6, l = tid & 63;
  int lr = l & 15, lg = l >> 4;
  int j = w*16 + lr;
  int emt = w & 1, ent = w >> 1;     // emit M-tile / F-tile; ent==3 idle

  {
    int* z = (int*)hb;
    #pragma unroll
    for (int i = 0; i < 8; ++i) z[tid + i*512] = 0;
    int* zx = (int*)xch;
    #pragma unroll
    for (int i = 0; i < 32; ++i) zx[tid + i*512] = 0;
  }

  // gate weights -> registers (once)
  bf16x8 wreg[8][4];
  #pragma unroll
  for (int kc = 0; kc < 8; ++kc)
    #pragma unroll
    for (int g = 0; g < 4; ++g)
      wreg[kc][g] = *(const bf16x8*)(Wc + (g*128 + j)*256 + kc*32 + lg*8);
  bf16x8 whr[4];
  {
    int fr = (ent < 3 ? ent : 0)*16 + lr;
    #pragma unroll
    for (int kc = 0; kc < 4; ++kc)
      whr[kc] = *(const bf16x8*)(Wh + fr*128 + kc*32 + lg*8);
  }

  float c[2][4];
  #pragma unroll
  for (int a = 0; a < 2; ++a)
    #pragma unroll
    for (int b = 0; b < 4; ++b) c[a][b] = 0.f;
  float bi = bias[j], bff = bias[128 + j], bg = bias[256 + j], bo = bias[384 + j];

  // staging: chunk = 4 timesteps = 3456 f32x4 items; ring slice = (t_abs)&7
  f32x4 rg[7];
  int tin[7], swz[7]; const float* gp[7]; bool act[7];
  #pragma unroll
  for (int k = 0; k < 7; ++k) {
    int i = tid + k*512;
    act[k] = i < 3456;
    int ii = act[k] ? i : 0;
    int a = ii / 1152, rem = ii - a*1152;
    int r = rem / 36, q = rem - r*36;
    int t_in = q / 9, fq = (q - t_in*9)*4;
    gp[k] = (a == 0 ? V : (a == 1 ? M : D)) + (size_t)(b0 + r)*1296 + q*4;
    tin[k] = t_in;
    swz[k] = ((r << 8) + ((a*36 + fq) << 1)) ^ ((r & 7) << 4);
  }
  auto load_chunk = [&](int ct) {
    #pragma unroll
    for (int k = 0; k < 7; ++k)
      if (act[k]) rg[k] = __builtin_nontemporal_load((const f32x4*)(gp[k] + ct*36));
  };
  auto write_chunk = [&](int ct) {
    #pragma unroll
    for (int k = 0; k < 7; ++k)
      if (act[k]) {
        short4 s = { f2bf(rg[k][0]), f2bf(rg[k][1]), f2bf(rg[k][2]), f2bf(rg[k][3]) };
        *(short4*)((char*)xch[(ct + tin[k]) & 7] + swz[k]) = s;
      }
  };

  load_chunk(0);
  write_chunk(0);
  __syncthreads();

  int cur = 0;
  for (int t = 0; t < 36; ++t) {
    int s = t & 3;

    // store previous step's xh slice (bf16; drains at this step's barrier)
    if (t > 0 && tid < 288) {
      int tprev = t - 1;
      int toutp = dir ? (35 - tprev) : tprev;
      int r = tid / 9, fq = (tid - r*9)*4;
      f32x4 v = *(const f32x4*)&xhs[tprev & 1][r*40 + fq];
      ushort4 sv = { (unsigned short)f2bf(v[0]), (unsigned short)f2bf(v[1]),
                     (unsigned short)f2bf(v[2]), (unsigned short)f2bf(v[3]) };
      *(ushort4*)(xhg + ((size_t)toutp*8192 + b0 + r)*36 + fq) = sv;
    }
    // prefetch next chunk into regs (consumed by write_chunk one step later)
    if (s == 2 && t < 32) load_chunk(t + 2);
    // commit prefetched chunk into ring slices (t+1..t+4)&7 — disjoint from slice t&7
    if (s == 3 && t < 35) write_chunk(t + 1);

    f32x4 ea = {0.f, 0.f, 0.f, 0.f};

    if (t < 35) {
      // gates = [x_t | h_t] @ Wc^T, weights from registers; emit fused at kc 4..7
      f32x4 acc[2][4] = {};
      #pragma unroll
      for (int kc = 0; kc < 8; ++kc) {
        const short* ub = (kc < 4) ? xch[t & 7] : hb[cur];
        int kk = (kc & 3)*32 + lg*8;
        bf16x8 af[2];
        #pragma unroll
        for (int mt = 0; mt < 2; ++mt) {
          int r = mt*16 + lr;
          af[mt] = *(bf16x8*)((char*)ub + (((r << 8) + (kk << 1)) ^ ((r & 7) << 4)));
        }
        #pragma unroll
        for (int g = 0; g < 4; ++g)
          #pragma unroll
          for (int mt = 0; mt < 2; ++mt)
            acc[mt][g] = __builtin_amdgcn_mfma_f32_16x16x32_bf16(af[mt], wreg[kc][g], acc[mt][g], 0, 0, 0);
        if (kc >= 4 && ent < 3)
          ea = __builtin_amdgcn_mfma_f32_16x16x32_bf16(af[emt], whr[kc - 4], ea, 0, 0, 0);
      }

      int nxt = cur ^ 1;
      #pragma unroll
      for (int mt = 0; mt < 2; ++mt) {
        #pragma unroll
        for (int reg = 0; reg < 4; ++reg) {
          float gi = sigm(acc[mt][0][reg] + bi);
          float gf = sigm(acc[mt][1][reg] + bff);
          float gg = tanhc(acc[mt][2][reg] + bg);
          float go = sigm(acc[mt][3][reg] + bo);
          float cc = gf * c[mt][reg] + gi * gg;
          c[mt][reg] = cc;
          float h = go * tanhc(cc);
          int rr = mt*16 + lg*4 + reg;
          *(short*)((char*)hb[nxt] + (((rr << 8) + (j << 1)) ^ ((rr & 7) << 4))) = f2bf(h);
        }
      }
      cur = nxt;
    } else if (ent < 3) {
      // t == 35: emit-only MFMA (pre-update h of the last step)
      #pragma unroll
      for (int kc = 0; kc < 4; ++kc) {
        int r = emt*16 + lr, kk = kc*32 + lg*8;
        bf16x8 af = *(bf16x8*)((char*)hb[cur] + (((r << 8) + (kk << 1)) ^ ((r & 7) << 4)));
        ea = __builtin_amdgcn_mfma_f32_16x16x32_bf16(af, whr[kc], ea, 0, 0, 0);
      }
    }

    // write emit result into xh LDS slice
    if (ent < 3) {
      int f = ent*16 + lr;
      if (f < 36) {
        #pragma unroll
        for (int reg = 0; reg < 4; ++reg)
          xhs[t & 1][(emt*16 + lg*4 + reg)*40 + f] = ea[reg];
      }
    }

    __syncthreads();
  }

  if (tid < 288) {   // final slice t=35
    int toutp = dir ? 0 : 35;
    int r = tid / 9, fq = (tid - r*9)*4;
    f32x4 v = *(const f32x4*)&xhs[1][r*40 + fq];
    ushort4 sv = { (unsigned short)f2bf(v[0]), (unsigned short)f2bf(v[1]),
                   (unsigned short)f2bf(v[2]), (unsigned short)f2bf(v[3]) };
    *(ushort4*)(xhg + ((size_t)toutp*8192 + b0 + r)*36 + fq) = sv;
  }
}

// Finish (t-major): block = 64 consecutive b at one t. alpha via MFMA, x_c, masked-L1 partials.
__global__ __launch_bounds__(256) void finish_kernel(
  const float* __restrict__ fv, const float* __restrict__ fm, const float* __restrict__ fd,
  const float* __restrict__ bwc, const float* __restrict__ bhist,
  const char* __restrict__ ws, float* __restrict__ out)
{
  const short* Wp = (const short*)(ws + WS_WP);
  float* lacc = (float*)(ws + WS_LACC);
  float* imp = out + 1;
  const unsigned short* xhf = (const unsigned short*)(out + XHF_OFF);
  const unsigned short* xhb = (const unsigned short*)(out + XHB_OFF);
  __shared__ short u2[8192];
  __shared__ float nacc, dacc;
  int tid = threadIdx.x, w = tid >> 6, l = tid & 63;
  int lr = l & 15, lg = l >> 4;
  int t = blockIdx.x >> 7;
  int b0 = (blockIdx.x & 127) * 64;

  if (tid == 0) { nacc = 0.f; dacc = 0.f; }

  for (int idx = tid; idx < 2048; idx += 256) {
    int r = idx >> 5, q = idx & 31;
    short4 s4 = {0, 0, 0, 0};
    if (q < 9) {
      f32x4 x4 = *(const f32x4*)(fm + ((size_t)(b0 + r)*36 + t)*36 + q*4);
      s4 = make_short4(f2bf(x4[0]), f2bf(x4[1]), f2bf(x4[2]), f2bf(x4[3]));
    } else if (q < 18) {
      f32x4 x4 = *(const f32x4*)(fd + ((size_t)(b0 + r)*36 + t)*36 + (q - 9)*4);
      s4 = make_short4(f2bf(x4[0]), f2bf(x4[1]), f2bf(x4[2]), f2bf(x4[3]));
    }
    int off = ((r << 8) + ((q*4) << 1)) ^ ((r & 7) << 4);
    *(short4*)((char*)u2 + off) = s4;
  }
  __syncthreads();

  f32x4 acc[3] = {};
  #pragma unroll
  for (int kc = 0; kc < 3; ++kc) {
    int r = w*16 + lr, k = kc*32 + lg*8;
    bf16x8 af = *(bf16x8*)((char*)u2 + (((r << 8) + (k << 1)) ^ ((r & 7) << 4)));
    #pragma unroll
    for (int nt = 0; nt < 3; ++nt) {
      int f = nt*16 + lr;
      bf16x8 bfr = *(const bf16x8*)(Wp + f*128 + kc*32 + lg*8);
      acc[nt] = __builtin_amdgcn_mfma_f32_16x16x32_bf16(af, bfr, acc[nt], 0, 0, 0);
    }
  }

  #pragma unroll
  for (int reg = 0; reg < 4; ++reg) {
    int rr = w*16 + lg*4 + reg;
    size_t b = b0 + rr;
    float ns = 0.f, ds = 0.f;
    #pragma unroll
    for (int nt = 0; nt < 3; ++nt) {
      int f = nt*16 + lr;
      if (f < 36) {
        size_t gi  = (b*36 + t)*36 + f;
        size_t gi2 = ((size_t)t*8192 + b)*36 + f;
        float alpha = sigm(acc[nt][reg] + bwc[f]);
        float xhv = bf2f(xhf[gi2]) + bf2f(xhb[gi2]) + bhist[f];
        float xc = alpha*xhv + 1.f - alpha;
        imp[gi] = xc;
        float mm = fm[gi];
        ns += fabsf(fv[gi] - xc) * mm;
        ds += mm;
      }
    }
    #pragma unroll
    for (int s = 1; s < 16; s <<= 1) { ns += __shfl_xor(ns, s); ds += __shfl_xor(ds, s); }
    if (lr == 0) { atomicAdd(&nacc, ns); atomicAdd(&dacc, ds); }
  }
  __syncthreads();
  if (tid == 0) {
    atomicAdd(lacc + t*16, nacc);
    atomicAdd(lacc + (36 + t)*16, dacc);
  }
}

__global__ void loss_final_kernel(const char* __restrict__ ws, float* __restrict__ out){
  const float* lacc = (const float*)(ws + WS_LACC);
  int t = threadIdx.x;
  float v = 0.f;
  if (t < 36) v = lacc[t*16] / (lacc[(36 + t)*16] + 1e-5f);
  #pragma unroll
  for (int s = 1; s < 64; s <<= 1) v += __shfl_xor(v, s);
  if (t == 0) out[0] = 0.3f * v;
}

extern "C" void kernel_launch(void* const* d_in, const int* in_sizes, int n_in,
                              void* d_out, int out_size, void* d_ws, size_t ws_size,
                              hipStream_t stream)
{
  const float* fv    = (const float*)d_in[0];
  const float* fm    = (const float*)d_in[1];
  const float* fd    = (const float*)d_in[2];
  const float* fe    = (const float*)d_in[3];
  const float* fem   = (const float*)d_in[4];
  const float* bv    = (const float*)d_in[5];
  const float* bm    = (const float*)d_in[6];
  const float* bd    = (const float*)d_in[7];
  const float* Wih   = (const float*)d_in[8];
  const float* Whh   = (const float*)d_in[9];
  const float* bih   = (const float*)d_in[10];
  const float* bhh   = (const float*)d_in[11];
  const float* Whist = (const float*)d_in[12];
  const float* bhist = (const float*)d_in[13];
  const float* Wwc   = (const float*)d_in[14];
  const float* bwc   = (const float*)d_in[15];
  float* out = (float*)d_out;
  char* ws = (char*)d_ws;

  prep_kernel<<<512, 256, 0, stream>>>(Wih, Whh, bih, bhh, Whist, Wwc, ws);
  lstm_kernel<<<512, 512, 0, stream>>>(fv, fm, fd, bv, bm, bd, ws, out);
  finish_kernel<<<4608, 256, 0, stream>>>(fv, fm, fd, bwc, bhist, ws, out);
  loss_final_kernel<<<1, 64, 0, stream>>>(ws, out);

  hipMemcpyAsync(out + 1 + (size_t)N_ELEM, fe,  (size_t)N_ELEM*4, hipMemcpyDeviceToDevice, stream);
  hipMemcpyAsync(out + 1 + 2*(size_t)N_ELEM, fem, (size_t)N_ELEM*4, hipMemcpyDeviceToDevice, stream);
}

// Round 8
// 521.384 us; speedup vs baseline: 1.4390x; 1.4390x over previous
//
#include <hip/hip_runtime.h>

#define B_ 8192
#define T_ 36
#define F_ 36
#define N_ELEM (B_*T_*F_)   // 10616832
// bf16 xh scratch (ushort), 16B-aligned, inside fe/fem out regions
#define XHF_OFF (N_ELEM + 4)
#define XHB_OFF (2*N_ELEM + 4)

typedef __attribute__((ext_vector_type(8))) short bf16x8;
typedef __attribute__((ext_vector_type(4))) float f32x4;

__device__ inline short f2bf(float x){
  union { float f; unsigned u; } v; v.f = x;
  unsigned r = v.u + 0x7FFFu + ((v.u >> 16) & 1u);
  return (short)(r >> 16);
}
__device__ inline float bf2f(unsigned short u){
  union { unsigned u32; float f; } v; v.u32 = ((unsigned)u) << 16; return v.f;
}
// R6 math, division replaced by v_rcp_f32 (1-ulp; exp path unchanged)
__device__ inline float sigm(float x){
  return __builtin_amdgcn_rcpf(1.f + __expf(-x));
}
__device__ inline float tanhc(float x){
  x = fminf(fmaxf(x, -15.f), 15.f);
  float e = __expf(-2.f*x);
  return (1.f - e) * __builtin_amdgcn_rcpf(1.f + e);
}

// ws layout (bytes)
#define WS_WC   0         // bf16 [512][256]: cols 0..107=W_ih, 108..127=0, 128..255=W_hh
#define WS_WH   262144    // bf16 [2][64][128]: W_hist per direction, rows 36..63 = 0
#define WS_WP   294912    // bf16 [48][128]:   W_wc padded (k 72..127 = 0)
#define WS_BIAS 307200    // f32 [512]: b_ih + b_hh
#define WS_LACC 309248    // f32 [72][16]: num[t] at [t][0], den[t] at [36+t][0]

__global__ __launch_bounds__(256) void prep_kernel(
    const float* __restrict__ Wih, const float* __restrict__ Whh,
    const float* __restrict__ bih, const float* __restrict__ bhh,
    const float* __restrict__ Whist, const float* __restrict__ Wwc,
    char* __restrict__ ws)
{
  short* Wc   = (short*)(ws + WS_WC);
  short* Wh   = (short*)(ws + WS_WH);
  short* Wp   = (short*)(ws + WS_WP);
  float* bias = (float*)(ws + WS_BIAS);
  float* lacc = (float*)(ws + WS_LACC);
  int i = blockIdx.x*256 + threadIdx.x;
  if (i < 131072){
    int n = i >> 8, k = i & 255;
    float v = 0.f;
    if (k < 108) v = Wih[n*108 + k];
    else if (k >= 128) v = Whh[n*128 + (k - 128)];
    Wc[i] = f2bf(v);
  }
  if (i < 16384){
    int d = i >> 13, f = (i >> 7) & 63, k = i & 127;
    Wh[i] = (f < 36) ? f2bf(Whist[f*256 + d*128 + k]) : (short)0;
  }
  if (i < 6144){
    int f = i >> 7, k = i & 127;
    Wp[i] = (f < 36 && k < 72) ? f2bf(Wwc[f*72 + k]) : (short)0;
  }
  if (i < 512) bias[i] = bih[i] + bhh[i];
  if (i < 1152) lacc[i] = 0.f;
}

// Persistent LSTM: block = 32 rows x 1 dir, 8 waves, grid 512 (2 rounds, 1 block/CU).
// Gate weights in registers. R6 skeleton. xh slices for ALL 36 steps accumulate in
// LDS (bf16) and are written out once at kernel end -> zero global stores in the
// step loop, so every per-step barrier's implicit vmcnt(0) drain is free.
__global__ __launch_bounds__(512, 2) void lstm_kernel(
  const float* __restrict__ fv, const float* __restrict__ fm, const float* __restrict__ fd,
  const float* __restrict__ bv, const float* __restrict__ bm, const float* __restrict__ bd,
  const char* __restrict__ ws, float* __restrict__ out)
{
  int dir = blockIdx.x & 1, tile = blockIdx.x >> 1;
  int b0 = tile * 32;
  const float* V = dir ? bv : fv;
  const float* M = dir ? bm : fm;
  const float* D = dir ? bd : fd;
  const short* Wc   = (const short*)(ws + WS_WC);
  const short* Wh   = (const short*)(ws + WS_WH) + dir*8192;
  const float* bias = (const float*)(ws + WS_BIAS);
  unsigned short* xhg = (unsigned short*)(out + (dir ? XHB_OFF : XHF_OFF)); // [t][b][f] bf16

  __shared__ short xch[4][4096];         // 4 t-slices [32][128] bf16, swizzled
  __shared__ short hb[2][4096];          // h double buffer [32][128] bf16, swizzled
  __shared__ unsigned short xha[36*1152]; // xh for all t: [36][32][36] bf16 (81 KB)

  int tid = threadIdx.x, w = tid >> 6, l = tid & 63;
  int lr = l & 15, lg = l >> 4;
  int j = w*16 + lr;
  int emt = w & 1, ent = w >> 1;     // emit M-tile / F-tile; ent==3 idle

  {
    int* z = (int*)hb;
    #pragma unroll
    for (int i = 0; i < 8; ++i) z[tid + i*512] = 0;
    int* zx = (int*)xch;
    #pragma unroll
    for (int i = 0; i < 16; ++i) zx[tid + i*512] = 0;
  }

  // gate weights -> registers (once)
  bf16x8 wreg[8][4];
  #pragma unroll
  for (int kc = 0; kc < 8; ++kc)
    #pragma unroll
    for (int g = 0; g < 4; ++g)
      wreg[kc][g] = *(const bf16x8*)(Wc + (g*128 + j)*256 + kc*32 + lg*8);
  bf16x8 whr[4];
  {
    int fr = (ent < 3 ? ent : 0)*16 + lr;
    #pragma unroll
    for (int kc = 0; kc < 4; ++kc)
      whr[kc] = *(const bf16x8*)(Wh + fr*128 + kc*32 + lg*8);
  }

  float c[2][4];
  #pragma unroll
  for (int a = 0; a < 2; ++a)
    #pragma unroll
    for (int b = 0; b < 4; ++b) c[a][b] = 0.f;
  float bi = bias[j], bff = bias[128 + j], bg = bias[256 + j], bo = bias[384 + j];

  f32x4 rg[7];
  auto load_chunk = [&](int ct) {
    #pragma unroll
    for (int k = 0; k < 7; ++k) {
      int i = tid + k*512;
      if (i < 3456) {
        int a = i / 1152, rem = i - a*1152;
        int r = rem / 36, q = rem - r*36;
        const float* src = (a == 0 ? V : (a == 1 ? M : D)) + (size_t)(b0 + r)*1296 + ct*36 + q*4;
        rg[k] = __builtin_nontemporal_load((const f32x4*)src);
      }
    }
  };
  auto write_chunk = [&]() {
    #pragma unroll
    for (int k = 0; k < 7; ++k) {
      int i = tid + k*512;
      if (i < 3456) {
        int a = i / 1152, rem = i - a*1152;
        int r = rem / 36, q = rem - r*36;
        int t_in = q / 9, fq = (q - t_in*9)*4;
        int kk = a*36 + fq;
        int off = ((r << 8) + (kk << 1)) ^ ((r & 7) << 4);
        short4 s = { f2bf(rg[k][0]), f2bf(rg[k][1]), f2bf(rg[k][2]), f2bf(rg[k][3]) };
        *(short4*)((char*)xch[t_in] + off) = s;
      }
    }
  };

  load_chunk(0);
  write_chunk();
  __syncthreads();

  int cur = 0;
  for (int t = 0; t < 36; ++t) {
    int s = t & 3;

    // prefetch next chunk into regs (consumed at next step's boundary)
    if (s == 2 && t < 32) load_chunk(t + 2);

    // emit xh_t = h_t @ W_hist^T -> LDS slice t (bf16), no global store
    if (ent < 3) {
      f32x4 ea = {0.f, 0.f, 0.f, 0.f};
      #pragma unroll
      for (int kc = 0; kc < 4; ++kc) {
        int r = emt*16 + lr, kk = kc*32 + lg*8;
        bf16x8 af = *(bf16x8*)((char*)hb[cur] + (((r << 8) + (kk << 1)) ^ ((r & 7) << 4)));
        ea = __builtin_amdgcn_mfma_f32_16x16x32_bf16(af, whr[kc], ea, 0, 0, 0);
      }
      int f = ent*16 + lr;
      if (f < 36) {
        #pragma unroll
        for (int reg = 0; reg < 4; ++reg)
          xha[t*1152 + (emt*16 + lg*4 + reg)*36 + f] = (unsigned short)f2bf(ea[reg]);
      }
    }

    if (t < 35) {
      // gates = [x_t | h_t] @ Wc^T, weights from registers
      f32x4 acc[2][4] = {};
      #pragma unroll
      for (int kc = 0; kc < 8; ++kc) {
        const short* ub = (kc < 4) ? xch[s] : hb[cur];
        int kk = (kc & 3)*32 + lg*8;
        bf16x8 af[2];
        #pragma unroll
        for (int mt = 0; mt < 2; ++mt) {
          int r = mt*16 + lr;
          af[mt] = *(bf16x8*)((char*)ub + (((r << 8) + (kk << 1)) ^ ((r & 7) << 4)));
        }
        #pragma unroll
        for (int g = 0; g < 4; ++g)
          #pragma unroll
          for (int mt = 0; mt < 2; ++mt)
            acc[mt][g] = __builtin_amdgcn_mfma_f32_16x16x32_bf16(af[mt], wreg[kc][g], acc[mt][g], 0, 0, 0);
      }

      int nxt = cur ^ 1;
      #pragma unroll
      for (int mt = 0; mt < 2; ++mt) {
        #pragma unroll
        for (int reg = 0; reg < 4; ++reg) {
          float gi = sigm(acc[mt][0][reg] + bi);
          float gf = sigm(acc[mt][1][reg] + bff);
          float gg = tanhc(acc[mt][2][reg] + bg);
          float go = sigm(acc[mt][3][reg] + bo);
          float cc = gf * c[mt][reg] + gi * gg;
          c[mt][reg] = cc;
          float h = go * tanhc(cc);
          int rr = mt*16 + lg*4 + reg;
          *(short*)((char*)hb[nxt] + (((rr << 8) + (j << 1)) ^ ((rr & 7) << 4))) = f2bf(h);
        }
      }
      if (s == 3) { __syncthreads(); write_chunk(); }
      __syncthreads();
      cur = nxt;
    } else {
      __syncthreads();   // final barrier: all xha writes visible
    }
  }

  // single batched writeout: 36 slices x 1152 ushorts, contiguous per slice
  for (int i = tid; i < 5184; i += 512) {
    int sl = i / 144, u = i - sl*144;
    int tout = dir ? 35 - sl : sl;
    bf16x8 v = *(const bf16x8*)(xha + sl*1152 + u*8);
    *(bf16x8*)(xhg + (size_t)tout*294912 + (size_t)b0*36 + u*8) = v;
  }
}

// Finish (t-major): block = 64 consecutive b at one t. alpha via MFMA, x_c, masked-L1 partials.
__global__ __launch_bounds__(256) void finish_kernel(
  const float* __restrict__ fv, const float* __restrict__ fm, const float* __restrict__ fd,
  const float* __restrict__ bwc, const float* __restrict__ bhist,
  const char* __restrict__ ws, float* __restrict__ out)
{
  const short* Wp = (const short*)(ws + WS_WP);
  float* lacc = (float*)(ws + WS_LACC);
  float* imp = out + 1;
  const unsigned short* xhf = (const unsigned short*)(out + XHF_OFF);
  const unsigned short* xhb = (const unsigned short*)(out + XHB_OFF);
  __shared__ short u2[8192];
  __shared__ float nacc, dacc;
  int tid = threadIdx.x, w = tid >> 6, l = tid & 63;
  int lr = l & 15, lg = l >> 4;
  int t = blockIdx.x >> 7;
  int b0 = (blockIdx.x & 127) * 64;

  if (tid == 0) { nacc = 0.f; dacc = 0.f; }

  for (int idx = tid; idx < 2048; idx += 256) {
    int r = idx >> 5, q = idx & 31;
    short4 s4 = {0, 0, 0, 0};
    if (q < 9) {
      f32x4 x4 = *(const f32x4*)(fm + ((size_t)(b0 + r)*36 + t)*36 + q*4);
      s4 = make_short4(f2bf(x4[0]), f2bf(x4[1]), f2bf(x4[2]), f2bf(x4[3]));
    } else if (q < 18) {
      f32x4 x4 = *(const f32x4*)(fd + ((size_t)(b0 + r)*36 + t)*36 + (q - 9)*4);
      s4 = make_short4(f2bf(x4[0]), f2bf(x4[1]), f2bf(x4[2]), f2bf(x4[3]));
    }
    int off = ((r << 8) + ((q*4) << 1)) ^ ((r & 7) << 4);
    *(short4*)((char*)u2 + off) = s4;
  }
  __syncthreads();

  f32x4 acc[3] = {};
  #pragma unroll
  for (int kc = 0; kc < 3; ++kc) {
    int r = w*16 + lr, k = kc*32 + lg*8;
    bf16x8 af = *(bf16x8*)((char*)u2 + (((r << 8) + (k << 1)) ^ ((r & 7) << 4)));
    #pragma unroll
    for (int nt = 0; nt < 3; ++nt) {
      int f = nt*16 + lr;
      bf16x8 bfr = *(const bf16x8*)(Wp + f*128 + kc*32 + lg*8);
      acc[nt] = __builtin_amdgcn_mfma_f32_16x16x32_bf16(af, bfr, acc[nt], 0, 0, 0);
    }
  }

  #pragma unroll
  for (int reg = 0; reg < 4; ++reg) {
    int rr = w*16 + lg*4 + reg;
    size_t b = b0 + rr;
    float ns = 0.f, ds = 0.f;
    #pragma unroll
    for (int nt = 0; nt < 3; ++nt) {
      int f = nt*16 + lr;
      if (f < 36) {
        size_t gi  = (b*36 + t)*36 + f;
        size_t gi2 = ((size_t)t*8192 + b)*36 + f;
        float alpha = sigm(acc[nt][reg] + bwc[f]);
        float xhv = bf2f(xhf[gi2]) + bf2f(xhb[gi2]) + bhist[f];
        float xc = alpha*xhv + 1.f - alpha;
        imp[gi] = xc;
        float mm = fm[gi];
        ns += fabsf(fv[gi] - xc) * mm;
        ds += mm;
      }
    }
    #pragma unroll
    for (int s = 1; s < 16; s <<= 1) { ns += __shfl_xor(ns, s); ds += __shfl_xor(ds, s); }
    if (lr == 0) { atomicAdd(&nacc, ns); atomicAdd(&dacc, ds); }
  }
  __syncthreads();
  if (tid == 0) {
    atomicAdd(lacc + t*16, nacc);
    atomicAdd(lacc + (36 + t)*16, dacc);
  }
}

__global__ void loss_final_kernel(const char* __restrict__ ws, float* __restrict__ out){
  const float* lacc = (const float*)(ws + WS_LACC);
  int t = threadIdx.x;
  float v = 0.f;
  if (t < 36) v = lacc[t*16] / (lacc[(36 + t)*16] + 1e-5f);
  #pragma unroll
  for (int s = 1; s < 64; s <<= 1) v += __shfl_xor(v, s);
  if (t == 0) out[0] = 0.3f * v;
}

extern "C" void kernel_launch(void* const* d_in, const int* in_sizes, int n_in,
                              void* d_out, int out_size, void* d_ws, size_t ws_size,
                              hipStream_t stream)
{
  const float* fv    = (const float*)d_in[0];
  const float* fm    = (const float*)d_in[1];
  const float* fd    = (const float*)d_in[2];
  const float* fe    = (const float*)d_in[3];
  const float* fem   = (const float*)d_in[4];
  const float* bv    = (const float*)d_in[5];
  const float* bm    = (const float*)d_in[6];
  const float* bd    = (const float*)d_in[7];
  const float* Wih   = (const float*)d_in[8];
  const float* Whh   = (const float*)d_in[9];
  const float* bih   = (const float*)d_in[10];
  const float* bhh   = (const float*)d_in[11];
  const float* Whist = (const float*)d_in[12];
  const float* bhist = (const float*)d_in[13];
  const float* Wwc   = (const float*)d_in[14];
  const float* bwc   = (const float*)d_in[15];
  float* out = (float*)d_out;
  char* ws = (char*)d_ws;

  prep_kernel<<<512, 256, 0, stream>>>(Wih, Whh, bih, bhh, Whist, Wwc, ws);
  lstm_kernel<<<512, 512, 0, stream>>>(fv, fm, fd, bv, bm, bd, ws, out);
  finish_kernel<<<4608, 256, 0, stream>>>(fv, fm, fd, bwc, bhist, ws, out);
  loss_final_kernel<<<1, 64, 0, stream>>>(ws, out);

  hipMemcpyAsync(out + 1 + (size_t)N_ELEM, fe,  (size_t)N_ELEM*4, hipMemcpyDeviceToDevice, stream);
  hipMemcpyAsync(out + 1 + 2*(size_t)N_ELEM, fem, (size_t)N_ELEM*4, hipMemcpyDeviceToDevice, stream);
}